// Round 6
// baseline (5848.274 us; speedup 1.0000x reference)
//
#include <hip/hip_runtime.h>
#include <cstdint>

__device__ __forceinline__ float sigm(float x) { return 1.f / (1.f + __expf(-x)); }
__device__ __forceinline__ float tanh_(float x) { return 1.f - 2.f / (1.f + __expf(2.f * x)); }

__device__ __forceinline__ void fma4(float4& a, float s, const float4& x) {
    a.x = fmaf(s, x.x, a.x); a.y = fmaf(s, x.y, a.y);
    a.z = fmaf(s, x.z, a.z); a.w = fmaf(s, x.w, a.w);
}

// ---------------- init: transpose states to [h][b], zero finisher counters ------
__global__ __launch_bounds__(256) void k_init(const float* __restrict__ h0i,
                                              const float* __restrict__ c0i,
                                              const float* __restrict__ feedi,
                                              float* h0T, float* h1T, float* c0T, float* c1T,
                                              float* feedT, int* cnt) {
    int t = blockIdx.x * 256 + threadIdx.x;  // 32768 = 512*64
    int hh = t >> 6, b = t & 63;
    h0T[t]   = h0i[b * 512 + hh];
    h1T[t]   = h0i[32768 + b * 512 + hh];
    c0T[t]   = c0i[b * 512 + hh];
    c1T[t]   = c0i[32768 + b * 512 + hh];
    feedT[t] = feedi[b * 512 + hh];
    if (blockIdx.x < 8) cnt[blockIdx.x * 256 + threadIdx.x] = 0;  // 2048 counters
}

// ---------------- one-time: C[m][n] = sum_k A[m][k] * B[k][n] (B row-major k,n) --
// M=4096, N=512, K=512. grid (64, 8), block 256.
__global__ __launch_bounds__(256) void k_gAB(const float* __restrict__ A,
                                             const float* __restrict__ B,
                                             float* __restrict__ C) {
    __shared__ float As[64][33];
    __shared__ float Bs[32][68];
    int m0 = blockIdx.x * 64, n0 = blockIdx.y * 64;
    int tid = threadIdx.x;
    int mg = tid >> 4, ng = tid & 15;
    float4 acc[4] = {};
    for (int kc = 0; kc < 16; kc++) {
        __syncthreads();
#pragma unroll
        for (int j = 0; j < 8; j++) {
            int idx = tid + j * 256;
            int r = idx >> 5, c = idx & 31;
            As[r][c] = A[(size_t)(m0 + r) * 512 + kc * 32 + c];
        }
#pragma unroll
        for (int j = 0; j < 8; j++) {
            int idx = tid + j * 256;
            int kk = idx >> 6, c = idx & 63;
            Bs[kk][c] = B[(size_t)(kc * 32 + kk) * 512 + n0 + c];
        }
        __syncthreads();
#pragma unroll 8
        for (int kk = 0; kk < 32; kk++) {
            float4 bv = *(const float4*)&Bs[kk][ng * 4];
#pragma unroll
            for (int i = 0; i < 4; i++) fma4(acc[i], As[mg * 4 + i][kk], bv);
        }
    }
#pragma unroll
    for (int i = 0; i < 4; i++)
        *(float4*)&C[(size_t)(m0 + mg * 4 + i) * 512 + n0 + ng * 4] = acc[i];
}

// ---------------- one-time: C[m][n] = sum_k A[m][k] * Bt[n][k] (Bt ld=ldBt) ------
__global__ __launch_bounds__(256) void k_gABt(const float* __restrict__ A,
                                              const float* __restrict__ Bt, int ldBt,
                                              float* __restrict__ C) {
    __shared__ float As[64][33];
    __shared__ float Bs[32][68];
    int m0 = blockIdx.x * 64, n0 = blockIdx.y * 64;
    int tid = threadIdx.x;
    int mg = tid >> 4, ng = tid & 15;
    float4 acc[4] = {};
    for (int kc = 0; kc < 16; kc++) {
        __syncthreads();
#pragma unroll
        for (int j = 0; j < 8; j++) {
            int idx = tid + j * 256;
            int r = idx >> 5, c = idx & 31;
            As[r][c] = A[(size_t)(m0 + r) * 512 + kc * 32 + c];
        }
#pragma unroll
        for (int j = 0; j < 2; j++) {
            int idx = tid + j * 256;        // 512 float4 loads cover 32k x 64n
            int c = idx & 63, kq = idx >> 6;
            float4 v = *(const float4*)(Bt + (size_t)(n0 + c) * ldBt + kc * 32 + kq * 4);
            Bs[kq * 4 + 0][c] = v.x;
            Bs[kq * 4 + 1][c] = v.y;
            Bs[kq * 4 + 2][c] = v.z;
            Bs[kq * 4 + 3][c] = v.w;
        }
        __syncthreads();
#pragma unroll 8
        for (int kk = 0; kk < 32; kk++) {
            float4 bv = *(const float4*)&Bs[kk][ng * 4];
#pragma unroll
            for (int i = 0; i < 4; i++) fma4(acc[i], As[mg * 4 + i][kk], bv);
        }
    }
#pragma unroll
    for (int i = 0; i < 4; i++)
        *(float4*)&C[(size_t)(m0 + mg * 4 + i) * 512 + n0 + ng * 4] = acc[i];
}

// ---------------- fused LSTM-layer GEMM + finisher cell ----------------
// Tile j (blockIdx.x, 32 tiles) owns gate rows {q*512 + j*16 + hhl}. K-split
// blockIdx.y (Kspl=128). Last split block per tile reduces partials + cell.
// layer0: segs = [emb-gather | feedT | h0Told], W = [Wih0 ld1024 | Whh0 ld512]
// layer1: segs = [h0Tnew | h1Told],            W = [Wih1 ld512  | Whh1 ld512]
__global__ __launch_bounds__(256) void k_glstm(
    int layer, int tstep, int nspl,
    const float* __restrict__ Wih, int ldih, int KW0,
    const float* __restrict__ Whh,
    const float* __restrict__ bih, const float* __restrict__ bhh,
    const float* __restrict__ s0T, const float* __restrict__ s1T,
    const float* __restrict__ s2T,
    const float* __restrict__ emb, const int* __restrict__ toks,
    float* __restrict__ P, int* __restrict__ cnt,
    float* __restrict__ hTnew, float* __restrict__ cT,
    float* __restrict__ outHf, float* __restrict__ outCf) {
    __shared__ float XT[128 * 68];
    __shared__ int isLast;
    int j = blockIdx.x;            // tile
    int kg = blockIdx.y * 128;     // K offset
    int tid = threadIdx.x;
    // ---- stage X chunk [128 k][64 b] ----
    int seg = kg >> 9, ko = kg & 511;
    if (layer == 0 && seg == 0) {
        int b = tid >> 2, q = tid & 3;
        const float* er = emb + (size_t)toks[tstep * 64 + b] * 512 + ko;
#pragma unroll
        for (int jj = 0; jj < 8; jj++) {
            int f4 = q + jj * 4;
            float4 v = *(const float4*)(er + f4 * 4);
            int kl = f4 * 4;
            XT[(kl + 0) * 68 + b] = v.x;
            XT[(kl + 1) * 68 + b] = v.y;
            XT[(kl + 2) * 68 + b] = v.z;
            XT[(kl + 3) * 68 + b] = v.w;
        }
    } else {
        const float* sT = (seg == 0) ? s0T : (seg == 1) ? s1T : s2T;
        const float4* src = (const float4*)(sT + (size_t)ko * 64);
#pragma unroll
        for (int jj = 0; jj < 8; jj++) {
            int f = tid + jj * 256;
            int k = f >> 4, bq = f & 15;
            *(float4*)&XT[k * 68 + bq * 4] = src[f];
        }
    }
    __syncthreads();
    // ---- 64x64 register-tiled partial GEMM over this 128-k chunk ----
    int i0 = (tid >> 4) * 4;   // tile-row group (0..60)
    int b0 = (tid & 15) * 4;   // batch group
    int q = i0 >> 4;           // gate quadrant (constant over the 4 rows)
    int grow0 = q * 512 + j * 16 + (i0 & 15);
    const float* wrow;
    size_t wld;
    if (kg < KW0) { wrow = Wih + (size_t)grow0 * ldih + kg; wld = (size_t)ldih; }
    else          { wrow = Whh + (size_t)grow0 * 512 + (kg - KW0); wld = 512; }
    float4 acc[4] = {};
#pragma unroll 4
    for (int k4 = 0; k4 < 32; k4++) {
        float4 wv[4], xb[4];
#pragma unroll
        for (int i = 0; i < 4; i++)
            wv[i] = *(const float4*)(wrow + (size_t)i * wld + k4 * 4);
#pragma unroll
        for (int kk = 0; kk < 4; kk++)
            xb[kk] = *(const float4*)&XT[(k4 * 4 + kk) * 68 + b0];
#pragma unroll
        for (int i = 0; i < 4; i++) {
            fma4(acc[i], wv[i].x, xb[0]);
            fma4(acc[i], wv[i].y, xb[1]);
            fma4(acc[i], wv[i].z, xb[2]);
            fma4(acc[i], wv[i].w, xb[3]);
        }
    }
    float* pout = P + (size_t)blockIdx.y * 2048 * 64;
#pragma unroll
    for (int i = 0; i < 4; i++)
        *(float4*)&pout[(size_t)(j * 64 + i0 + i) * 64 + b0] = acc[i];
    // ---- finisher election ----
    __threadfence();
    if (tid == 0) {
        int old = atomicAdd(&cnt[j], 1);
        isLast = (old == nspl - 1) ? 1 : 0;
    }
    __syncthreads();
    if (!isLast) return;
    __threadfence();
    // cell update for hh in [j*16, j*16+16) x 64 b
    for (int e = tid; e < 1024; e += 256) {
        int hhl = e >> 6, b = e & 63;
        int hh = j * 16 + hhl;
        float g[4];
#pragma unroll
        for (int qq = 0; qq < 4; qq++) {
            float v = bih[qq * 512 + hh] + bhh[qq * 512 + hh];
            int tr = j * 64 + qq * 16 + hhl;
            for (int s = 0; s < nspl; s++) v += P[((size_t)s * 2048 + tr) * 64 + b];
            g[qq] = v;
        }
        float c = cT[hh * 64 + b];
        float cn = sigm(g[1]) * c + sigm(g[0]) * tanh_(g[2]);
        float hn = sigm(g[3]) * tanh_(cn);
        cT[hh * 64 + b] = cn;
        hTnew[hh * 64 + b] = hn;
        if (tstep == 31) { outHf[b * 512 + hh] = hn; outCf[b * 512 + hh] = cn; }
    }
}

// ---------------- scores+softmax (blocks 0..63) || y = Wout_h * h1 (64..95) -----
__global__ __launch_bounds__(256) void k_sy(int tstep, const float* __restrict__ ctxA,
                                            const float* __restrict__ h1T,
                                            const float* __restrict__ Wout,
                                            float* __restrict__ y,
                                            float* __restrict__ pArena,
                                            float* __restrict__ outAtt) {
    __shared__ float XT[128 * 68];
    __shared__ float h1l[512];
    __shared__ float sc4[64][4];
    int tid = threadIdx.x;
    if (blockIdx.x < 64) {
        int b = blockIdx.x;
        for (int i = tid; i < 512; i += 256) h1l[i] = h1T[i * 64 + b];
        __syncthreads();
        int s = tid >> 2, part = tid & 3;
        const float4* row = (const float4*)(ctxA + ((size_t)s * 64 + b) * 512 + part * 128);
        float acc = 0.f;
        for (int kb = 0; kb < 32; kb++) {
            float4 cv = row[kb];
            int k = part * 128 + kb * 4;
            acc = fmaf(cv.x, h1l[k], acc);
            acc = fmaf(cv.y, h1l[k + 1], acc);
            acc = fmaf(cv.z, h1l[k + 2], acc);
            acc = fmaf(cv.w, h1l[k + 3], acc);
        }
        sc4[s][part] = acc;
        __syncthreads();
        if (tid < 64) {
            int ss = tid;
            float v = sc4[ss][0] + sc4[ss][1] + sc4[ss][2] + sc4[ss][3];
            float m = v;
            for (int off = 32; off; off >>= 1) m = fmaxf(m, __shfl_xor(m, off));
            float e = __expf(v - m);
            float sum = e;
            for (int off = 32; off; off >>= 1) sum += __shfl_xor(sum, off);
            float p = e / sum;
            pArena[b * 64 + ss] = p;
            outAtt[((size_t)tstep * 64 + b) * 64 + ss] = p;
        }
    } else {
        int r0 = (blockIdx.x - 64) * 16;        // 32 blocks x 16 out-rows
        int irow = r0 + (tid >> 4);
        int b0 = (tid & 15) * 4;
        float4 acc = {};
        for (int kc = 0; kc < 4; kc++) {
            __syncthreads();
            const float4* src = (const float4*)(h1T + (size_t)kc * 128 * 64);
#pragma unroll
            for (int jj = 0; jj < 8; jj++) {
                int f = tid + jj * 256;
                int k = f >> 4, bq = f & 15;
                *(float4*)&XT[k * 68 + bq * 4] = src[f];
            }
            __syncthreads();
            const float* wrow = Wout + (size_t)irow * 1024 + 512 + kc * 128;
#pragma unroll 4
            for (int k4 = 0; k4 < 32; k4++) {
                float4 wv = *(const float4*)(wrow + k4 * 4);
                float4 xb[4];
#pragma unroll
                for (int kk = 0; kk < 4; kk++)
                    xb[kk] = *(const float4*)&XT[(k4 * 4 + kk) * 68 + b0];
                fma4(acc, wv.x, xb[0]);
                fma4(acc, wv.y, xb[1]);
                fma4(acc, wv.z, xb[2]);
                fma4(acc, wv.w, xb[3]);
            }
        }
        *(float4*)&y[(size_t)irow * 64 + b0] = acc;
    }
}

// ---------------- blend: attn_h = tanh(sum_s p*ctxW + y); outputs + feed --------
__global__ __launch_bounds__(256) void k_blend(int tstep, const float* __restrict__ ctxW,
                                               const float* __restrict__ y,
                                               const float* __restrict__ pArena,
                                               float* __restrict__ feedT,
                                               float* __restrict__ outMain,
                                               float* __restrict__ outFeedf) {
    __shared__ float pl[64];
    int b = blockIdx.x >> 1;
    int o = (blockIdx.x & 1) * 256 + threadIdx.x;
    if (threadIdx.x < 64) pl[threadIdx.x] = pArena[b * 64 + threadIdx.x];
    __syncthreads();
    float acc = y[(size_t)o * 64 + b];
    for (int s = 0; s < 64; s++)
        acc = fmaf(pl[s], ctxW[((size_t)s * 64 + b) * 512 + o], acc);
    float ah = tanh_(acc);
    outMain[((size_t)tstep * 64 + b) * 512 + o] = ah;
    feedT[o * 64 + b] = ah;
    if (tstep == 31) outFeedf[b * 512 + o] = ah;
}

extern "C" void kernel_launch(void* const* d_in, const int* in_sizes, int n_in,
                              void* d_out, int out_size, void* d_ws, size_t ws_size,
                              hipStream_t stream) {
    const int*   toks  = (const int*)d_in[0];
    const float* ctx   = (const float*)d_in[2];
    const float* h0i   = (const float*)d_in[3];
    const float* c0i   = (const float*)d_in[4];
    const float* feedi = (const float*)d_in[5];
    const float* emb   = (const float*)d_in[6];
    const float* Wih0  = (const float*)d_in[7];
    const float* Whh0  = (const float*)d_in[8];
    const float* bih0  = (const float*)d_in[9];
    const float* bhh0  = (const float*)d_in[10];
    const float* Wih1  = (const float*)d_in[11];
    const float* Whh1  = (const float*)d_in[12];
    const float* bih1  = (const float*)d_in[13];
    const float* bhh1  = (const float*)d_in[14];
    const float* Wa    = (const float*)d_in[15];
    const float* Wout  = (const float*)d_in[16];

    char* ws = (char*)d_ws;
    size_t off = 0;
    float* ctxA   = (float*)(ws + off); off += 4096ull * 512 * 4;   // 8 MB
    float* ctxW   = (float*)(ws + off); off += 4096ull * 512 * 4;   // 8 MB
    float* P      = (float*)(ws + off); off += 12ull * 2048 * 64 * 4; // 6 MB
    float* h0A    = (float*)(ws + off); off += 131072;
    float* h0B    = (float*)(ws + off); off += 131072;
    float* h1A    = (float*)(ws + off); off += 131072;
    float* h1B    = (float*)(ws + off); off += 131072;
    float* c0T    = (float*)(ws + off); off += 131072;
    float* c1T    = (float*)(ws + off); off += 131072;
    float* feedT  = (float*)(ws + off); off += 131072;
    float* yArena = (float*)(ws + off); off += 131072;
    float* pArena = (float*)(ws + off); off += 16384;
    int*   cnt    = (int*)(ws + off);  off += 8192;   // 2048 counters

    float* out      = (float*)d_out;
    float* outMain  = out;             // [T,B,H]
    float* outAtt   = out + 1048576;   // [T,B,S]
    float* outHf    = out + 1179648;   // [L,B,H]
    float* outCf    = out + 1245184;   // [L,B,H]
    float* outFeedf = out + 1310720;   // [B,H]

    hipLaunchKernelGGL(k_init, dim3(128), dim3(256), 0, stream,
                       h0i, c0i, feedi, h0A, h1A, c0T, c1T, feedT, cnt);
    // ctxA[sb][i] = sum_j ctx[sb][j] * Wa[j][i]
    hipLaunchKernelGGL(k_gAB, dim3(64, 8), dim3(256), 0, stream, ctx, Wa, ctxA);
    // ctxW[sb][o] = sum_h ctx[sb][h] * Wout[o][h]  (cvec half of Wout)
    hipLaunchKernelGGL(k_gABt, dim3(64, 8), dim3(256), 0, stream, ctx, Wout, 1024, ctxW);

    for (int t = 0; t < 32; t++) {
        float* h0in  = (t & 1) ? h0B : h0A;
        float* h0out = (t & 1) ? h0A : h0B;
        float* h1in  = (t & 1) ? h1B : h1A;
        float* h1out = (t & 1) ? h1A : h1B;
        int* cnt0 = cnt + t * 64;
        int* cnt1 = cnt + t * 64 + 32;
        // layer 0: K=1536 = [emb | feed | h0old], 12 splits
        hipLaunchKernelGGL(k_glstm, dim3(32, 12), dim3(256), 0, stream,
                           0, t, 12, Wih0, 1024, 1024, Whh0, bih0, bhh0,
                           (const float*)nullptr, feedT, h0in, emb, toks,
                           P, cnt0, h0out, c0T, outHf, outCf);
        // layer 1: K=1024 = [h0new | h1old], 8 splits
        hipLaunchKernelGGL(k_glstm, dim3(32, 8), dim3(256), 0, stream,
                           1, t, 8, Wih1, 512, 512, Whh1, bih1, bhh1,
                           h0out, h1in, (const float*)nullptr, emb, toks,
                           P, cnt1, h1out, c1T, outHf + 32768, outCf + 32768);
        // scores+softmax (64 blocks) || y = Wout_h * h1new (32 blocks)
        hipLaunchKernelGGL(k_sy, dim3(96), dim3(256), 0, stream,
                           t, ctxA, h1out, Wout, yArena, pArena, outAtt);
        // blend + tanh + outputs + next feed
        hipLaunchKernelGGL(k_blend, dim3(128), dim3(256), 0, stream,
                           t, ctxW, yArena, pArena, feedT, outMain, outFeedf);
    }
}